// Round 1
// baseline (529.323 us; speedup 1.0000x reference)
//
#include <hip/hip_runtime.h>

// LISTA fused kernel, MI355X gfx950.
// Shapes: X[4][64][65536] f32, We[256][64] f32, S[3][256][256] f32, thetas[4] f32,
// out[4][256][65536] f32.  M = 4*65536 = 262144 pixels.
//
// Structure: 1 WG (256 thr = 4 waves) per TM=64 pixel tile. Wave w owns dict
// slice [64w, 64w+64). MFMA 16x16x32 bf16 with A = weights (dict rows),
// B = activations (pixels) from LDS -> C/D has col=pixel, row=dict, so each
// lane holds 4 consecutive dict entries -> b64 packed LDS epilogue writes and
// coalesced final stores. S[i] fragments persistent in registers per iter.

#define TM 64
#define LA_STRIDE 264   // 256 + 8 bf16 pad: keeps 16B align (528B rows), 2-way banks max
#define LX_STRIDE 72    // 64 + 8

typedef short bf16x8 __attribute__((ext_vector_type(8)));
typedef float f32x4 __attribute__((ext_vector_type(4)));

__device__ __forceinline__ unsigned short f2bf(float f) {
  union { float f; unsigned u; } a; a.f = f;
  return (unsigned short)((a.u + 0x7fffu + ((a.u >> 16) & 1u)) >> 16); // RNE
}
__device__ __forceinline__ float bf2f(unsigned hbits16) {
  union { unsigned u; float f; } a; a.u = hbits16 << 16; return a.f;
}
__device__ __forceinline__ float sshrink(float x, float th) {
  return x > th ? x - th : (x < -th ? x + th : 0.0f);
}

// Load an 8-element A-fragment of a [N][K]-row-major weight matrix.
template<bool WBF16>
__device__ __forceinline__ bf16x8 load_wfrag(const unsigned short* wbase,
                                             const float* fbase, int off) {
  if constexpr (WBF16) {
    return *reinterpret_cast<const bf16x8*>(wbase + off);
  } else {
    const float* p = fbase + off;
    float4 f0 = *reinterpret_cast<const float4*>(p);
    float4 f1 = *reinterpret_cast<const float4*>(p + 4);
    bf16x8 t;
    t[0] = (short)f2bf(f0.x); t[1] = (short)f2bf(f0.y);
    t[2] = (short)f2bf(f0.z); t[3] = (short)f2bf(f0.w);
    t[4] = (short)f2bf(f1.x); t[5] = (short)f2bf(f1.y);
    t[6] = (short)f2bf(f1.z); t[7] = (short)f2bf(f1.w);
    return t;
  }
}

__global__ void convert_weights(const float* __restrict__ We,
                                const float* __restrict__ S,
                                unsigned short* __restrict__ w) {
  int gid = blockIdx.x * 256 + threadIdx.x;
  if (gid < 256 * 64) w[gid] = f2bf(We[gid]);
  else if (gid < 256 * 64 + 3 * 256 * 256) w[gid] = f2bf(S[gid - 256 * 64]);
}

template<bool WBF16>
__global__ __launch_bounds__(256, 2)
void lista_kernel(const float* __restrict__ X, const float* __restrict__ Wef,
                  const float* __restrict__ Sf, const float* __restrict__ thetas,
                  float* __restrict__ out,
                  const unsigned short* __restrict__ wWe,
                  const unsigned short* __restrict__ wS) {
  __shared__ unsigned short lA[TM * LA_STRIDE]; // logits tile [pixel][dict], bf16
  __shared__ unsigned short lX[TM * LX_STRIDE]; // input tile  [pixel][chan], bf16

  const int tid  = threadIdx.x;
  const int wave = tid >> 6;
  const int lane = tid & 63;
  const int l16  = lane & 15;
  const int quad = lane >> 4;
  const int p0   = blockIdx.x * TM;
  const int b0   = p0 >> 16;        // image index (65536 spatials per image)
  const int s0   = p0 & 65535;      // spatial offset within image
  const int d_base = wave * 64;     // this wave's dict slice

  // ---- stage X tile -> lX (bf16). Coalesced: fixed c, 64 consecutive spatials.
  {
    const int m = tid & 63;
    const int cg = tid >> 6;
#pragma unroll
    for (int j = 0; j < 16; ++j) {
      const int c = cg * 16 + j;
      float v = X[(b0 * 64 + c) * 65536 + s0 + m];
      lX[m * LX_STRIDE + c] = f2bf(v);
    }
  }

  // ---- We fragments (A-operand: d = l16 row, c = quad*8+j contiguous)
  bf16x8 Wf1[4][2];
#pragma unroll
  for (int dt = 0; dt < 4; ++dt)
#pragma unroll
    for (int ks = 0; ks < 2; ++ks) {
      const int off = (d_base + dt * 16 + l16) * 64 + ks * 32 + quad * 8;
      Wf1[dt][ks] = load_wfrag<WBF16>(wWe, Wef, off);
    }

  __syncthreads();

  // ---- GEMM1: B0[d][p] = sum_c We[d][c] * X[p][c]
  f32x4 acc[4][4];
#pragma unroll
  for (int dt = 0; dt < 4; ++dt)
#pragma unroll
    for (int pt = 0; pt < 4; ++pt) acc[dt][pt] = (f32x4){0.f, 0.f, 0.f, 0.f};

#pragma unroll
  for (int ks = 0; ks < 2; ++ks) {
    bf16x8 bfr[4];
#pragma unroll
    for (int pt = 0; pt < 4; ++pt)
      bfr[pt] = *reinterpret_cast<const bf16x8*>(
          &lX[(pt * 16 + l16) * LX_STRIDE + ks * 32 + quad * 8]);
#pragma unroll
    for (int pt = 0; pt < 4; ++pt)
#pragma unroll
      for (int dt = 0; dt < 4; ++dt)
        acc[dt][pt] = __builtin_amdgcn_mfma_f32_16x16x32_bf16(
            Wf1[dt][ks], bfr[pt], acc[dt][pt], 0, 0, 0);
  }

  // ---- phase-0 epilogue: keep B0 packed bf16 in regs; logits0 = shrink(B0) -> lA
  const float th0 = thetas[0];
  unsigned B0pk[4][4][2];
#pragma unroll
  for (int dt = 0; dt < 4; ++dt)
#pragma unroll
    for (int pt = 0; pt < 4; ++pt) {
      float v0 = acc[dt][pt][0], v1 = acc[dt][pt][1];
      float v2 = acc[dt][pt][2], v3 = acc[dt][pt][3];
      B0pk[dt][pt][0] = (unsigned)f2bf(v0) | ((unsigned)f2bf(v1) << 16);
      B0pk[dt][pt][1] = (unsigned)f2bf(v2) | ((unsigned)f2bf(v3) << 16);
      float l0 = sshrink(v0, th0), l1 = sshrink(v1, th0);
      float l2 = sshrink(v2, th0), l3 = sshrink(v3, th0);
      unsigned pk0 = (unsigned)f2bf(l0) | ((unsigned)f2bf(l1) << 16);
      unsigned pk1 = (unsigned)f2bf(l2) | ((unsigned)f2bf(l3) << 16);
      const int row = pt * 16 + l16;
      const int col = d_base + dt * 16 + quad * 4;
      *reinterpret_cast<uint2*>(&lA[row * LA_STRIDE + col]) = make_uint2(pk0, pk1);
    }

  // ---- LISTA iterations
  for (int it = 0; it < 3; ++it) {
    const float th = thetas[it + 1];

    // persistent S[i] fragments for this wave's dict slice (128 VGPRs);
    // issued before the barrier so they fly during the barrier wait.
    bf16x8 Wf[4][8];
#pragma unroll
    for (int dt = 0; dt < 4; ++dt)
#pragma unroll
      for (int ks = 0; ks < 8; ++ks) {
        const int off = it * 65536 + (d_base + dt * 16 + l16) * 256 + ks * 32 + quad * 8;
        Wf[dt][ks] = load_wfrag<WBF16>(wS, Sf, off);
      }

    __syncthreads(); // prior lA writes -> this iter's reads

#pragma unroll
    for (int dt = 0; dt < 4; ++dt)
#pragma unroll
      for (int pt = 0; pt < 4; ++pt) acc[dt][pt] = (f32x4){0.f, 0.f, 0.f, 0.f};

#pragma unroll
    for (int ks = 0; ks < 8; ++ks) {
      bf16x8 bfr[4];
#pragma unroll
      for (int pt = 0; pt < 4; ++pt)
        bfr[pt] = *reinterpret_cast<const bf16x8*>(
            &lA[(pt * 16 + l16) * LA_STRIDE + ks * 32 + quad * 8]);
#pragma unroll
      for (int pt = 0; pt < 4; ++pt)
#pragma unroll
        for (int dt = 0; dt < 4; ++dt)
          acc[dt][pt] = __builtin_amdgcn_mfma_f32_16x16x32_bf16(
              Wf[dt][ks], bfr[pt], acc[dt][pt], 0, 0, 0);
    }

    __syncthreads(); // all waves done reading lA before it is overwritten

#pragma unroll
    for (int dt = 0; dt < 4; ++dt)
#pragma unroll
      for (int pt = 0; pt < 4; ++pt) {
        float b0v0 = bf2f(B0pk[dt][pt][0] & 0xffffu);
        float b0v1 = bf2f(B0pk[dt][pt][0] >> 16);
        float b0v2 = bf2f(B0pk[dt][pt][1] & 0xffffu);
        float b0v3 = bf2f(B0pk[dt][pt][1] >> 16);
        float l0 = sshrink(acc[dt][pt][0] + b0v0, th);
        float l1 = sshrink(acc[dt][pt][1] + b0v1, th);
        float l2 = sshrink(acc[dt][pt][2] + b0v2, th);
        float l3 = sshrink(acc[dt][pt][3] + b0v3, th);
        if (it < 2) {
          unsigned pk0 = (unsigned)f2bf(l0) | ((unsigned)f2bf(l1) << 16);
          unsigned pk1 = (unsigned)f2bf(l2) | ((unsigned)f2bf(l3) << 16);
          const int row = pt * 16 + l16;
          const int col = d_base + dt * 16 + quad * 4;
          *reinterpret_cast<uint2*>(&lA[row * LA_STRIDE + col]) = make_uint2(pk0, pk1);
        } else {
          // out[b][d][s]: 16 lanes of a quad write 64B contiguous spatials
          const int d = d_base + dt * 16 + quad * 4;
          const size_t ob = (size_t)(b0 * 256 + d) * 65536 + s0 + pt * 16 + l16;
          out[ob] = l0;
          out[ob + 65536] = l1;
          out[ob + 2 * 65536] = l2;
          out[ob + 3 * 65536] = l3;
        }
      }
  }
}

extern "C" void kernel_launch(void* const* d_in, const int* in_sizes, int n_in,
                              void* d_out, int out_size, void* d_ws, size_t ws_size,
                              hipStream_t stream) {
  const float* X  = (const float*)d_in[0];
  const float* We = (const float*)d_in[1];
  const float* S  = (const float*)d_in[2];
  const float* th = (const float*)d_in[3];
  float* out = (float*)d_out;

  const size_t welems = 256 * 64 + 3 * 256 * 256; // 212992
  const bool wb = ws_size >= welems * 2;

  if (wb) {
    unsigned short* w = (unsigned short*)d_ws;
    convert_weights<<<dim3(832), dim3(256), 0, stream>>>(We, S, w);
    lista_kernel<true><<<dim3(4096), dim3(256), 0, stream>>>(
        X, We, S, th, out, w, w + 256 * 64);
  } else {
    lista_kernel<false><<<dim3(4096), dim3(256), 0, stream>>>(
        X, We, S, th, out, nullptr, nullptr);
  }
}